// Round 4
// baseline (30.560 us; speedup 1.0000x reference)
//
#include <hip/hip_runtime.h>

#define NN 2048

__device__ __forceinline__ float cubic3(float px, float py, float b0, float b1, float b2) {
    // b0*px^3 + b1*px^2*py + b2*px*py^2
    return px * (px * (px * b0 + py * b1) + (py * py) * b2);
}

__global__ __launch_bounds__(256) void FlowEmbedder_kernel(
    const float* __restrict__ x,      // [N,2]
    const float* __restrict__ p,      // [3,2]
    float* __restrict__ out)          // [N,N]
{
    int tid = blockIdx.x * 256 + threadIdx.x;   // 2 outputs per thread
    int i  = tid >> 10;                          // row (1024 threads per row)
    int j2 = tid & 1023;                         // pair-of-columns index

    float2 xi = ((const float2*)x)[i];
    float4 xj = ((const float4*)x)[j2];          // x[2*j2], x[2*j2+1]

    float p0 = p[0], p1 = p[1], p2 = p[2], p3 = p[3], p4 = p[4], p5 = p[5];

    const float NL  = -1.4426950408889634f;      // -log2(e)
    const float NL3 = -4.3280851226668903f;      // -3*log2(e)  (comb folded)

    float X = xi.x, Y = xi.y;

    // ---------- pair A: monomial coeffs of exp2-arg as cubic in t ----------
    float dxA = xj.x - X, dyA = xj.y - Y;
    float dA  = sqrtf(dxA * dxA + dyA * dyA);                 // precise sqrt (mask boundary)
    float sfA = (dA > 0.0f) ? __builtin_amdgcn_rcpf(dA) * 0.1f : 0.0f;
    float uxA = dxA * sfA, uyA = dyA * sfA;                   // per-step displacement
    float nA  = fminf(floorf(dA / 0.1f), 15.0f);              // IEEE div: exact mask boundary
    float bA0 = NL  * (p0 * dxA + p1 * dyA);
    float bA1 = NL3 * (p2 * dxA + p3 * dyA);
    float bA2 = NL3 * (p4 * dxA + p5 * dyA);
    float f0A = cubic3(X,            Y,            bA0, bA1, bA2);
    float f1A = cubic3(X + uxA,      Y + uyA,      bA0, bA1, bA2);
    float f2A = cubic3(X + 2.f*uxA,  Y + 2.f*uyA,  bA0, bA1, bA2);
    float c3A = cubic3(uxA, uyA, bA0, bA1, bA2);              // leading coeff directly
    float c2A = 0.5f * (f2A - 2.0f * f1A + f0A) - 3.0f * c3A;
    float c1A = (f1A - f0A) - c2A - c3A;
    float c0A = f0A;

    // ---------- pair B ----------
    float dxB = xj.z - X, dyB = xj.w - Y;
    float dB  = sqrtf(dxB * dxB + dyB * dyB);
    float sfB = (dB > 0.0f) ? __builtin_amdgcn_rcpf(dB) * 0.1f : 0.0f;
    float uxB = dxB * sfB, uyB = dyB * sfB;
    float nB  = fminf(floorf(dB / 0.1f), 15.0f);
    float bB0 = NL  * (p0 * dxB + p1 * dyB);
    float bB1 = NL3 * (p2 * dxB + p3 * dyB);
    float bB2 = NL3 * (p4 * dxB + p5 * dyB);
    float f0B = cubic3(X,            Y,            bB0, bB1, bB2);
    float f1B = cubic3(X + uxB,      Y + uyB,      bB0, bB1, bB2);
    float f2B = cubic3(X + 2.f*uxB,  Y + 2.f*uyB,  bB0, bB1, bB2);
    float c3B = cubic3(uxB, uyB, bB0, bB1, bB2);
    float c2B = 0.5f * (f2B - 2.0f * f1B + f0B) - 3.0f * c3B;
    float c1B = (f1B - f0B) - c2B - c3B;
    float c0B = f0B;

    // ---------- fixed-trip, branch-free, fully unrolled ----------
    float sA = 0.0f, sB = 0.0f;
    #pragma unroll
    for (int t = 0; t < 16; ++t) {
        float tf = (float)t;                     // compile-time constant
        float dvA = c0A + tf * (c1A + tf * (c2A + tf * c3A));  // independent per t
        float dvB = c0B + tf * (c1B + tf * (c2B + tf * c3B));
        float eA = __builtin_amdgcn_exp2f(dvA);
        float eB = __builtin_amdgcn_exp2f(dvB);
        sA += (tf <= nA) ? eA : 0.0f;            // cmp + cndmask + add
        sB += (tf <= nB) ? eB : 0.0f;
    }

    // cost = 0.1 * sum((1 + 4*exp(-dot))/5) = 0.02*(count + 4*sum_exp)
    float cA = 0.02f * (nA + 1.0f + 4.0f * sA);
    float cB = 0.02f * (nB + 1.0f + 4.0f * sB);
    ((float2*)out)[tid] = make_float2(cA, cB);
}

extern "C" void kernel_launch(void* const* d_in, const int* in_sizes, int n_in,
                              void* d_out, int out_size, void* d_ws, size_t ws_size,
                              hipStream_t stream) {
    const float* x = (const float*)d_in[0];   // embedded_points [2048,2]
    const float* p = (const float*)d_in[1];   // flow_field_parameters [3,2]
    float* out = (float*)d_out;               // [2048,2048]

    const int total_threads = NN * NN / 2;    // 2 outputs per thread
    FlowEmbedder_kernel<<<total_threads / 256, 256, 0, stream>>>(x, p, out);
}

// Round 5
// 24.116 us; speedup vs baseline: 1.2672x; 1.2672x over previous
//
#include <hip/hip_runtime.h>

#define NN 2048

__device__ __forceinline__ float cubic3(float px, float py, float b0, float b1, float b2) {
    // b0*px^3 + b1*px^2*py + b2*px*py^2
    return px * (px * (px * b0 + py * b1) + (py * py) * b2);
}

__global__ __launch_bounds__(256, 8) void FlowEmbedder_kernel(
    const float* __restrict__ x,      // [N,2]
    const float* __restrict__ p,      // [3,2]
    float* __restrict__ out)          // [N,N]
{
    int tid = blockIdx.x * 256 + threadIdx.x;   // 2 outputs per thread
    int i  = tid >> 10;                          // row (1024 threads per row)
    int j2 = tid & 1023;                         // pair-of-columns index

    float2 xi = ((const float2*)x)[i];
    float4 xj = ((const float4*)x)[j2];          // x[2*j2], x[2*j2+1]

    float p0 = p[0], p1 = p[1], p2 = p[2], p3 = p[3], p4 = p[4], p5 = p[5];

    const float NL  = -1.4426950408889634f;      // -log2(e)
    const float NL3 = -4.3280851226668903f;      // -3*log2(e)  (comb folded)

    float X = xi.x, Y = xi.y;

    // ---------- pair A ----------
    float dxA = xj.x - X, dyA = xj.y - Y;
    float dA  = sqrtf(dxA * dxA + dyA * dyA);                 // precise sqrt (mask boundary)
    float sfA = (dA > 0.0f) ? __builtin_amdgcn_rcpf(dA) * 0.1f : 0.0f;
    float uxA = dxA * sfA, uyA = dyA * sfA;
    int   nA  = (int)floorf(dA / 0.1f); nA = nA > 15 ? 15 : nA;  // IEEE div: exact boundary
    float bA0 = NL  * (p0 * dxA + p1 * dyA);
    float bA1 = NL3 * (p2 * dxA + p3 * dyA);
    float bA2 = NL3 * (p4 * dxA + p5 * dyA);
    float f0A = cubic3(X,            Y,            bA0, bA1, bA2);
    float f1A = cubic3(X + uxA,      Y + uyA,      bA0, bA1, bA2);
    float f2A = cubic3(X + 2.f*uxA,  Y + 2.f*uyA,  bA0, bA1, bA2);
    float c3A = cubic3(uxA, uyA, bA0, bA1, bA2);
    float dvA = f0A;
    float d1A = f1A - f0A;
    float d2A = f2A - 2.0f * f1A + f0A;
    float d3A = 6.0f * c3A;

    // ---------- pair B ----------
    float dxB = xj.z - X, dyB = xj.w - Y;
    float dB  = sqrtf(dxB * dxB + dyB * dyB);
    float sfB = (dB > 0.0f) ? __builtin_amdgcn_rcpf(dB) * 0.1f : 0.0f;
    float uxB = dxB * sfB, uyB = dyB * sfB;
    int   nB  = (int)floorf(dB / 0.1f); nB = nB > 15 ? 15 : nB;
    float bB0 = NL  * (p0 * dxB + p1 * dyB);
    float bB1 = NL3 * (p2 * dxB + p3 * dyB);
    float bB2 = NL3 * (p4 * dxB + p5 * dyB);
    float f0B = cubic3(X,            Y,            bB0, bB1, bB2);
    float f1B = cubic3(X + uxB,      Y + uyB,      bB0, bB1, bB2);
    float f2B = cubic3(X + 2.f*uxB,  Y + 2.f*uyB,  bB0, bB1, bB2);
    float c3B = cubic3(uxB, uyB, bB0, bB1, bB2);
    float dvB = f0B;
    float d1B = f1B - f0B;
    float d2B = f2B - 2.0f * f1B + f0B;
    float d3B = 6.0f * c3B;

    int maxT = nA > nB ? nA : nB;

    // Software-pipelined: exp issued at iteration t is accumulated at t+1,
    // so the per-iteration critical path is just the FD adds.
    float sA = 0.0f, sB = 0.0f;
    float mA = 0.0f, mB = 0.0f;     // masked exp from previous iteration
    #pragma unroll 2
    for (int t = 0; t <= maxT; ++t) {
        float eA = __builtin_amdgcn_exp2f(dvA);
        float eB = __builtin_amdgcn_exp2f(dvB);
        sA += mA;
        sB += mB;
        mA = (t <= nA) ? eA : 0.0f;   // int cmp + cndmask
        mB = (t <= nB) ? eB : 0.0f;
        dvA += d1A; d1A += d2A; d2A += d3A;
        dvB += d1B; d1B += d2B; d2B += d3B;
    }
    sA += mA;
    sB += mB;

    // cost = 0.1 * sum((1 + 4*exp(-dot))/5) = 0.02*(count + 4*sum_exp)
    float cA = 0.02f * ((float)(nA + 1) + 4.0f * sA);
    float cB = 0.02f * ((float)(nB + 1) + 4.0f * sB);
    ((float2*)out)[tid] = make_float2(cA, cB);
}

extern "C" void kernel_launch(void* const* d_in, const int* in_sizes, int n_in,
                              void* d_out, int out_size, void* d_ws, size_t ws_size,
                              hipStream_t stream) {
    const float* x = (const float*)d_in[0];   // embedded_points [2048,2]
    const float* p = (const float*)d_in[1];   // flow_field_parameters [3,2]
    float* out = (float*)d_out;               // [2048,2048]

    const int total_threads = NN * NN / 2;    // 2 outputs per thread
    FlowEmbedder_kernel<<<total_threads / 256, 256, 0, stream>>>(x, p, out);
}

// Round 6
// 19.790 us; speedup vs baseline: 1.5442x; 1.2186x over previous
//
#include <hip/hip_runtime.h>

#define NN 2048

typedef float f32x2 __attribute__((ext_vector_type(2)));

__device__ __forceinline__ f32x2 cub2(f32x2 px, f32x2 py, f32x2 b0, f32x2 b1, f32x2 b2) {
    // b0*px^3 + b1*px^2*py + b2*px*py^2, elementwise (packs to v_pk_fma/v_pk_mul)
    return px * (px * (px * b0 + py * b1) + (py * py) * b2);
}

__global__ __launch_bounds__(256, 8) void FlowEmbedder_kernel(
    const float* __restrict__ x,      // [N,2]
    const float* __restrict__ p,      // [3,2]
    float* __restrict__ out)          // [N,N]
{
    int tid = blockIdx.x * 256 + threadIdx.x;   // 2 outputs per thread
    int i  = tid >> 10;                          // row (1024 threads per row)
    int j2 = tid & 1023;                         // pair-of-columns index

    float2 xi = ((const float2*)x)[i];
    float4 xj = ((const float4*)x)[j2];          // x[2*j2], x[2*j2+1]

    float p0 = p[0], p1 = p[1], p2 = p[2], p3 = p[3], p4 = p[4], p5 = p[5];
    const float NL  = -1.4426950408889634f;      // -log2(e)
    const float NL3 = -4.3280851226668903f;      // -3*log2(e) (comb folded)

    // lane .x = pair A, lane .y = pair B — all symmetric math in packed f32x2
    f32x2 dx = {xj.x - xi.x, xj.z - xi.x};
    f32x2 dy = {xj.y - xi.y, xj.w - xi.y};
    f32x2 d2 = dx * dx + dy * dy;
    f32x2 dist = { __builtin_amdgcn_sqrtf(d2.x), __builtin_amdgcn_sqrtf(d2.y) };
    f32x2 sf = { dist.x > 0.0f ? __builtin_amdgcn_rcpf(dist.x) * 0.1f : 0.0f,
                 dist.y > 0.0f ? __builtin_amdgcn_rcpf(dist.y) * 0.1f : 0.0f };
    f32x2 ux = dx * sf, uy = dy * sf;            // per-step displacement

    int nA = (int)fminf(floorf(dist.x * 10.0f), 15.0f);
    int nB = (int)fminf(floorf(dist.y * 10.0f), 15.0f);
    int maxT = nA > nB ? nA : nB;

    f32x2 b0 = NL  * (p0 * dx + p1 * dy);
    f32x2 b1 = NL3 * (p2 * dx + p3 * dy);
    f32x2 b2 = NL3 * (p4 * dx + p5 * dy);

    f32x2 X = {xi.x, xi.x}, Y = {xi.y, xi.y};
    f32x2 x1 = X + ux,  y1 = Y + uy;
    f32x2 x2 = x1 + ux, y2 = y1 + uy;
    f32x2 f0 = cub2(X,  Y,  b0, b1, b2);         // exp2-arg at t=0,1,2 + leading coeff
    f32x2 f1 = cub2(x1, y1, b0, b1, b2);
    f32x2 f2 = cub2(x2, y2, b0, b1, b2);
    f32x2 c3 = cub2(ux, uy, b0, b1, b2);

    f32x2 d1 = f1 - f0;                          // forward differences of the cubic
    f32x2 dd = (f2 - 2.0f * f1) + f0;
    f32x2 d3 = 6.0f * c3;

    // multiplicative FD: E_t = exp2(dv_t);  E*=G, G*=H, H*=K  (no exp in the loop)
    f32x2 E = { __builtin_amdgcn_exp2f(f0.x), __builtin_amdgcn_exp2f(f0.y) };
    f32x2 G = { __builtin_amdgcn_exp2f(d1.x), __builtin_amdgcn_exp2f(d1.y) };
    f32x2 H = { __builtin_amdgcn_exp2f(dd.x), __builtin_amdgcn_exp2f(dd.y) };
    f32x2 K = { __builtin_amdgcn_exp2f(d3.x), __builtin_amdgcn_exp2f(d3.y) };

    float sA = 0.0f, sB = 0.0f;
    #pragma unroll 2
    for (int t = 0; t <= maxT; ++t) {
        sA += (t <= nA) ? E.x : 0.0f;            // cndmask blocks tail inf/NaN
        sB += (t <= nB) ? E.y : 0.0f;
        E *= G; G *= H; H *= K;                  // 3 × v_pk_mul_f32
    }

    // cost = 0.1 * sum((1 + 4*exp(-dot))/5) = 0.02*(count + 4*sum_exp)
    float cA = 0.02f * ((float)(nA + 1) + 4.0f * sA);
    float cB = 0.02f * ((float)(nB + 1) + 4.0f * sB);
    ((float2*)out)[tid] = make_float2(cA, cB);
}

extern "C" void kernel_launch(void* const* d_in, const int* in_sizes, int n_in,
                              void* d_out, int out_size, void* d_ws, size_t ws_size,
                              hipStream_t stream) {
    const float* x = (const float*)d_in[0];   // embedded_points [2048,2]
    const float* p = (const float*)d_in[1];   // flow_field_parameters [3,2]
    float* out = (float*)d_out;               // [2048,2048]

    const int total_threads = NN * NN / 2;    // 2 outputs per thread
    FlowEmbedder_kernel<<<total_threads / 256, 256, 0, stream>>>(x, p, out);
}

// Round 7
// 19.440 us; speedup vs baseline: 1.5720x; 1.0180x over previous
//
#include <hip/hip_runtime.h>

#define NN 2048

typedef float f32x2 __attribute__((ext_vector_type(2)));

__device__ __forceinline__ f32x2 cub2(f32x2 px, f32x2 py, f32x2 b0, f32x2 b1, f32x2 b2) {
    // b0*px^3 + b1*px^2*py + b2*px*py^2, elementwise (v_pk_fma/v_pk_mul)
    return px * (px * (px * b0 + py * b1) + (py * py) * b2);
}

// Builds one channel (2 pairs) of multiplicative-FD state from positions.
// Outputs: E,G,H,K (exp2 FD chain), nf (float trip bound per pair).
struct Chan { f32x2 E, G, H, K, nf; };

__device__ __forceinline__ Chan make_chan(float X, float Y, float4 xj,
                                          float p0, float p1, float p2,
                                          float p3, float p4, float p5) {
    const float NL  = -1.4426950408889634f;   // -log2(e)
    const float NL3 = -4.3280851226668903f;   // -3*log2(e) (comb folded)

    f32x2 dx = {xj.x - X, xj.z - X};
    f32x2 dy = {xj.y - Y, xj.w - Y};
    f32x2 d2 = dx * dx + dy * dy;
    f32x2 dist = { __builtin_amdgcn_sqrtf(d2.x), __builtin_amdgcn_sqrtf(d2.y) };
    f32x2 sf = { dist.x > 0.0f ? __builtin_amdgcn_rcpf(dist.x) * 0.1f : 0.0f,
                 dist.y > 0.0f ? __builtin_amdgcn_rcpf(dist.y) * 0.1f : 0.0f };
    f32x2 ux = dx * sf, uy = dy * sf;

    Chan c;
    c.nf = { fminf(floorf(dist.x * 10.0f), 15.0f),
             fminf(floorf(dist.y * 10.0f), 15.0f) };

    f32x2 b0 = NL  * (p0 * dx + p1 * dy);
    f32x2 b1 = NL3 * (p2 * dx + p3 * dy);
    f32x2 b2 = NL3 * (p4 * dx + p5 * dy);

    f32x2 Xv = {X, X}, Yv = {Y, Y};
    f32x2 x1 = Xv + ux,  y1 = Yv + uy;
    f32x2 x2 = x1 + ux,  y2 = y1 + uy;
    f32x2 f0 = cub2(Xv, Yv, b0, b1, b2);
    f32x2 f1 = cub2(x1, y1, b0, b1, b2);
    f32x2 f2 = cub2(x2, y2, b0, b1, b2);
    f32x2 c3 = cub2(ux, uy, b0, b1, b2);

    f32x2 d1 = f1 - f0;
    f32x2 dd = (f2 - 2.0f * f1) + f0;
    f32x2 d3 = 6.0f * c3;

    c.E = { __builtin_amdgcn_exp2f(f0.x), __builtin_amdgcn_exp2f(f0.y) };
    c.G = { __builtin_amdgcn_exp2f(d1.x), __builtin_amdgcn_exp2f(d1.y) };
    c.H = { __builtin_amdgcn_exp2f(dd.x), __builtin_amdgcn_exp2f(dd.y) };
    c.K = { __builtin_amdgcn_exp2f(d3.x), __builtin_amdgcn_exp2f(d3.y) };
    return c;
}

__global__ __launch_bounds__(256, 8) void FlowEmbedder_kernel(
    const float* __restrict__ x,      // [N,2]
    const float* __restrict__ p,      // [3,2]
    float* __restrict__ out)          // [N,N]
{
    int tid = blockIdx.x * 256 + threadIdx.x;   // 4 outputs per thread
    int i  = tid >> 9;                           // row (512 threads per row)
    int j4 = tid & 511;                          // group of 4 columns

    float2 xi  = ((const float2*)x)[i];
    float4 xjC = ((const float4*)x)[2 * j4];     // cols 4j4, 4j4+1
    float4 xjD = ((const float4*)x)[2 * j4 + 1]; // cols 4j4+2, 4j4+3

    float p0 = p[0], p1 = p[1], p2 = p[2], p3 = p[3], p4 = p[4], p5 = p[5];

    Chan C = make_chan(xi.x, xi.y, xjC, p0, p1, p2, p3, p4, p5);
    Chan D = make_chan(xi.x, xi.y, xjD, p0, p1, p2, p3, p4, p5);

    float maxT = fmaxf(fmaxf(C.nf.x, C.nf.y), fmaxf(D.nf.x, D.nf.y));

    f32x2 sC = {0.0f, 0.0f}, sD = {0.0f, 0.0f};
    #pragma unroll 2
    for (float tf = 0.0f; tf <= maxT; tf += 1.0f) {
        f32x2 mC, mD;                            // cndmask on E value: inf-safe
        mC.x = (tf <= C.nf.x) ? C.E.x : 0.0f;
        mC.y = (tf <= C.nf.y) ? C.E.y : 0.0f;
        mD.x = (tf <= D.nf.x) ? D.E.x : 0.0f;
        mD.y = (tf <= D.nf.y) ? D.E.y : 0.0f;
        sC += mC;                                // v_pk_add_f32
        sD += mD;
        C.E *= C.G; C.G *= C.H; C.H *= C.K;      // 6 × v_pk_mul_f32
        D.E *= D.G; D.G *= D.H; D.H *= D.K;
    }

    // cost = 0.02*(n+1) + 0.08*sum_exp  (packed epilogue)
    f32x2 cc = 0.02f * C.nf + 0.02f + 0.08f * sC;
    f32x2 cd = 0.02f * D.nf + 0.02f + 0.08f * sD;
    float4 res = { cc.x, cc.y, cd.x, cd.y };
    ((float4*)out)[tid] = res;
}

extern "C" void kernel_launch(void* const* d_in, const int* in_sizes, int n_in,
                              void* d_out, int out_size, void* d_ws, size_t ws_size,
                              hipStream_t stream) {
    const float* x = (const float*)d_in[0];   // embedded_points [2048,2]
    const float* p = (const float*)d_in[1];   // flow_field_parameters [3,2]
    float* out = (float*)d_out;               // [2048,2048]

    const int total_threads = NN * NN / 4;    // 4 outputs per thread
    FlowEmbedder_kernel<<<total_threads / 256, 256, 0, stream>>>(x, p, out);
}